// Round 14
// baseline (143.157 us; speedup 1.0000x reference)
//
#include <hip/hip_runtime.h>
#include <hip/hip_bf16.h>

// Head: x(8,2048,1024) fp32 @ {Wq,Wk,Wv}(1024,128) fp32
//   -> causal softmax((QK^T)/32) @ V -> out FP32.
// Ledger: best 136.8us (R13) = simple 2-phase qkv (41us) + QBLK32 attn with
// K-dbuf @(256,2) (live ~212 vs cap 256 -> no spill; R4/R12's collapses were
// cap-168 margin violations). qkv intra-block pipelines failed 3x: with
// 2 blocks/CU the INTER-block overlap (A stages while B computes) already
// pipelines; barriers just disturb it.
// R22: qkv K-loop split into 2 halves of 512 -> LDS 64KB->32KB -> 4
// blocks/CU (32 waves/CU) at launch_bounds(512,8); measured VGPR 52-56
// fits the 64 cap. Staging pattern / B-loads / MFMA / epilogue bits
// unchanged. attn/prep frozen (R13 winners).

typedef __attribute__((ext_vector_type(8))) short bf16x8;   // 8 bf16 = 4 VGPRs
typedef __attribute__((ext_vector_type(4))) float f32x4;    // MFMA C/D frag

#define NB   8
#define TT   2048
#define CDIM 1024
#define HD   128
#define NTOK (NB * TT)   // 16384
#define NW   384

using bf16 = __hip_bfloat16;

__device__ __forceinline__ short f2bs(float f) {          // RNE bf16
    unsigned u = __builtin_bit_cast(unsigned, f);
    return (short)((u + 0x7FFF + ((u >> 16) & 1)) >> 16);
}

// ---------- prep: pack W into MFMA B-fragment order ----------
__global__ __launch_bounds__(256) void prep_w_kernel(
        const float* __restrict__ Wq, const float* __restrict__ Wk,
        const float* __restrict__ Wv, bf16* __restrict__ Wp) {
    const int f  = blockIdx.x * 256 + threadIdx.x;        // 0..49151
    const int l  = f & 63;
    const int nt = (f >> 6) % 24;
    const int sl = f / 1536;
    const int ln = l & 15, quad = l >> 4;
    const int n  = nt * 16 + ln;                          // 0..383
    const int w  = n >> 7, h = n & 127;
    const float* W = (w == 0) ? Wq : (w == 1) ? Wk : Wv;
    const int k0 = sl * 32 + quad * 8;
    bf16x8 frag;
    #pragma unroll
    for (int j = 0; j < 8; j++)
        frag[j] = f2bs(W[(long)(k0 + j) * HD + h]);
    *(bf16x8*)((short*)Wp + (long)f * 8) = frag;          // coalesced 16B/thread
}

// ---------- QKV projection: grid 512, block 512, 4 blocks/CU ----------
// 32 rows/block = one attn key-tile; wave w: cols [48w,48w+48).
// K processed in 2 halves of 512: stage half h (32KB frag-linear LDS),
// barrier, 16-slice MFMA loop, repeat. Epilogue identical to R13.
__global__ __launch_bounds__(512, 8) void qkv_proj_kernel(
        const float* __restrict__ x, const bf16* __restrict__ Wp,
        bf16* __restrict__ Q, bf16* __restrict__ Kp, bf16* __restrict__ Vp) {
    __shared__ __align__(16) short aLDS[32 * 32 * 16];      // 32KB
    const int tid  = threadIdx.x;
    const int wave = tid >> 6, lane = tid & 63;
    const int quad = lane >> 4, ln = lane & 15;
    const long mbase = (long)blockIdx.x * 32;

    const f32x4 zero = {0.f, 0.f, 0.f, 0.f};
    f32x4 acc[2][3];
    #pragma unroll
    for (int mt = 0; mt < 2; mt++)
        #pragma unroll
        for (int nt = 0; nt < 3; nt++) acc[mt][nt] = zero;

    const short* bp = (const short*)Wp + (long)wave * 1536 + lane * 8;

    #pragma unroll
    for (int h = 0; h < 2; h++) {
        if (h) __syncthreads();                 // prev half's reads done
        // ----- stage half h: 4 frags/thread, frag-linear -----
        // fid = fmt*1024 + fsl*64 + fl (fsl 0..15); dst byte = fid*16.
        #pragma unroll
        for (int j = 0; j < 4; j++) {
            const int fid = j * 512 + tid;
            const int fl  = fid & 63;
            const int fsl = (fid >> 6) & 15;
            const int fmt = fid >> 10;
            const float4* src = (const float4*)(
                x + (mbase + fmt * 16 + (fl & 15)) * CDIM
                  + (h * 16 + fsl) * 32 + (fl >> 4) * 8);
            float4 u = src[0], v = src[1];
            bf16x8 fr;
            fr[0] = f2bs(u.x); fr[1] = f2bs(u.y); fr[2] = f2bs(u.z); fr[3] = f2bs(u.w);
            fr[4] = f2bs(v.x); fr[5] = f2bs(v.y); fr[6] = f2bs(v.z); fr[7] = f2bs(v.w);
            *(bf16x8*)(aLDS + (long)fid * 8) = fr;
        }
        __syncthreads();

        // ----- 16-slice MFMA loop -----
        const short* a0 = aLDS + lane * 8;      // + sl*512 ; mt=1 at +8192
        #pragma unroll 4
        for (int sl = 0; sl < 16; sl++) {
            const int sg = h * 16 + sl;
            bf16x8 af0 = *(const bf16x8*)(a0 + sl * 512);
            bf16x8 af1 = *(const bf16x8*)(a0 + 8192 + sl * 512);
            bf16x8 b0  = *(const bf16x8*)(bp + (long)sg * 12288);
            bf16x8 b1  = *(const bf16x8*)(bp + (long)sg * 12288 + 512);
            bf16x8 b2  = *(const bf16x8*)(bp + (long)sg * 12288 + 1024);
            acc[0][0] = __builtin_amdgcn_mfma_f32_16x16x32_bf16(af0, b0, acc[0][0], 0, 0, 0);
            acc[0][1] = __builtin_amdgcn_mfma_f32_16x16x32_bf16(af0, b1, acc[0][1], 0, 0, 0);
            acc[0][2] = __builtin_amdgcn_mfma_f32_16x16x32_bf16(af0, b2, acc[0][2], 0, 0, 0);
            acc[1][0] = __builtin_amdgcn_mfma_f32_16x16x32_bf16(af1, b0, acc[1][0], 0, 0, 0);
            acc[1][1] = __builtin_amdgcn_mfma_f32_16x16x32_bf16(af1, b1, acc[1][1], 0, 0, 0);
            acc[1][2] = __builtin_amdgcn_mfma_f32_16x16x32_bf16(af1, b2, acc[1][2], 0, 0, 0);
        }
    }

    // ----- epilogue: Q -> global; K,V -> LDS transpose -> packed tiles -----
    __syncthreads();                                      // aLDS dead for all waves
    short* kT = aLDS;                                     // [32][136] shorts, 8704B
    short* vT = aLDS + 8192;                              // [128][40] shorts, 10240B

    #pragma unroll
    for (int mt = 0; mt < 2; mt++) {
        #pragma unroll
        for (int nt = 0; nt < 3; nt++) {
            const int n = wave * 48 + nt * 16 + ln;
            #pragma unroll
            for (int r = 0; r < 4; r++) {
                const int row = mt * 16 + quad * 4 + r;   // local token 0..31
                const short hv = f2bs(acc[mt][nt][r]);
                if (n < 128) {
                    long g = mbase + row;
                    int b = (int)(g >> 11), t = (int)(g & (TT - 1));
                    Q[((long)b * TT + t) * HD + n] = __builtin_bit_cast(bf16, hv);
                } else if (n < 256) {
                    kT[row * 136 + (n - 128)] = hv;       // K[tok][h]
                } else {
                    vT[(n - 256) * 40 + row] = hv;        // V^T[h][tok]
                }
            }
        }
    }
    __syncthreads();

    // packed frag writes: wave w emits K frag w (kc=w>>1, nt=w&1) and V frag w
    {
        const long tile = blockIdx.x;                     // = b*64 + jt
        const int  kc = wave >> 1, ntk = wave & 1;
        bf16x8 kv = *(const bf16x8*)&kT[(ntk*16 + ln)*136 + kc*32 + quad*8];
        *(bf16x8*)((short*)Kp + (tile*8 + wave)*512 + lane*8) = kv;
        bf16x8 vv = *(const bf16x8*)&vT[(wave*16 + ln)*40 + quad*8];
        *(bf16x8*)((short*)Vp + (tile*8 + wave)*512 + lane*8) = vv;
    }
}

// ---------- causal flash attention (QBLK=32, K double-buffered) ----------
// Frozen R13 winner. Static-max softmax; grid 512, block 256 = 4 waves;
// waves split the key range, partials tree-reduced in LDS (4 -> 2 -> 1).
// K/V frag loads = contiguous 1KB wave-loads; next tile's K prefetched
// during softmax+PV (live ~212 under the (256,2) cap of 256).
#define ATTN_TILE32(CUR, NXT)                                                    \
  {                                                                              \
    const int j0 = kt * 32;                                                      \
    const short* vbase = Vpb + (long)kt * 4096 + lane * 8;                       \
    bf16x8 vf[8];                                                                \
    _Pragma("unroll")                                                            \
    for (int ht = 0; ht < 8; ht++)                                               \
        vf[ht] = *(const bf16x8*)(vbase + ht*512);                               \
    if (kt + 1 < t1) {                                                           \
        const short* nkb = Kpb + (long)(kt + 1) * 4096 + lane * 8;               \
        _Pragma("unroll")                                                        \
        for (int kc = 0; kc < 4; kc++)                                           \
            _Pragma("unroll")                                                    \
            for (int ntk = 0; ntk < 2; ntk++)                                    \
                NXT[kc][ntk] = *(const bf16x8*)(nkb + (kc*2 + ntk)*512);         \
    }                                                                            \
    f32x4 s[2][2];                                                               \
    s[0][0] = zero; s[0][1] = zero; s[1][0] = zero; s[1][1] = zero;              \
    _Pragma("unroll")                                                            \
    for (int kc = 0; kc < 4; kc++)                                               \
        _Pragma("unroll")                                                        \
        for (int mt = 0; mt < 2; mt++) {                                         \
            s[mt][0] = __builtin_amdgcn_mfma_f32_16x16x32_bf16(qf[mt][kc], CUR[kc][0], s[mt][0], 0, 0, 0); \
            s[mt][1] = __builtin_amdgcn_mfma_f32_16x16x32_bf16(qf[mt][kc], CUR[kc][1], s[mt][1], 0, 0, 0); \
        }                                                                        \
    short* pb = pwave + (kt & 1) * 1280;                                         \
    _Pragma("unroll")                                                            \
    for (int mt = 0; mt < 2; mt++)                                               \
        _Pragma("unroll")                                                        \
        for (int r = 0; r < 4; r++) {                                            \
            const int q = qb + mt*16 + quad*4 + r;                               \
            _Pragma("unroll")                                                    \
            for (int ntk = 0; ntk < 2; ntk++) {                                  \
                float p = __expf(s[mt][ntk][r] * 0.03125f);                      \
                if (j0 + ntk*16 + ln > q) p = 0.f;                               \
                li[mt][r] += p;                                                  \
                pb[(mt*16 + quad*4 + r)*40 + ntk*16 + ln] = f2bs(p);             \
            }                                                                    \
        }                                                                        \
    bf16x8 pf[2];                                                                \
    _Pragma("unroll")                                                            \
    for (int mt = 0; mt < 2; mt++)                                               \
        pf[mt] = *(const bf16x8*)&pb[(mt*16 + ln)*40 + quad*8];                  \
    _Pragma("unroll")                                                            \
    for (int mt = 0; mt < 2; mt++)                                               \
        _Pragma("unroll")                                                        \
        for (int ht = 0; ht < 8; ht++)                                           \
            o[mt][ht] = __builtin_amdgcn_mfma_f32_16x16x32_bf16(pf[mt], vf[ht], o[mt][ht], 0, 0, 0); \
    kt++;                                                                        \
  }

__global__ __launch_bounds__(256, 2) void attn_kernel(
        const bf16* __restrict__ Q, const bf16* __restrict__ Kp,
        const bf16* __restrict__ Vp, float* __restrict__ out) {
    // union: pbuf (4 waves x 2 x [32][40] shorts = 20480B, live in loop)
    //        red [2][32][128] f32 = 32768B + redl [2][32] f32 = 256B, after
    __shared__ __align__(16) char smem[33024];

    const int tid  = threadIdx.x;
    const int wave = tid >> 6, lane = tid & 63;
    const int quad = lane >> 4, ln = lane & 15;
    // block -> (b, qi): balanced pairing {63-r, r}
    const int b   = blockIdx.x & 7;
    const int idx = blockIdx.x >> 3;           // 0..63
    const int qi  = (idx >> 5) ? (idx & 31) : 63 - (idx & 31);
    const int qb  = qi * 32;
    const int ntiles = qi + 1;                 // key tiles of 32
    const int t0 = (ntiles * wave) >> 2;
    const int t1 = (ntiles * (wave + 1)) >> 2;

    const bf16*  Qb  = Q + (long)b * TT * HD;
    const short* Kpb = (const short*)Kp + (long)b * 64 * 4096;  // 4096 sh/tile
    const short* Vpb = (const short*)Vp + (long)b * 64 * 4096;

    short* pwave = (short*)smem + wave * 2560;             // 2 x [32][40]

    bf16x8 qf[2][4];
    #pragma unroll
    for (int mt = 0; mt < 2; mt++)
        #pragma unroll
        for (int kc = 0; kc < 4; kc++)
            qf[mt][kc] = *(const bf16x8*)(Qb + (long)(qb + mt*16 + ln)*HD + kc*32 + quad*8);

    const f32x4 zero = {0.f, 0.f, 0.f, 0.f};
    f32x4 o[2][8];
    #pragma unroll
    for (int mt = 0; mt < 2; mt++)
        #pragma unroll
        for (int ht = 0; ht < 8; ht++) o[mt][ht] = zero;
    float li[2][4] = {{0.f,0.f,0.f,0.f},{0.f,0.f,0.f,0.f}};

    bf16x8 kfA[4][2], kfB[4][2];
    if (t0 < t1) {
        const short* kb0 = Kpb + (long)t0 * 4096 + lane * 8;
        #pragma unroll
        for (int kc = 0; kc < 4; kc++)
            #pragma unroll
            for (int ntk = 0; ntk < 2; ntk++)
                kfA[kc][ntk] = *(const bf16x8*)(kb0 + (kc*2 + ntk)*512);
    }
    int kt = t0;
    while (kt < t1) {
        ATTN_TILE32(kfA, kfB)
        if (kt >= t1) break;
        ATTN_TILE32(kfB, kfA)
    }

    // reduce li across the 16 lanes sharing each row
    #pragma unroll
    for (int mt = 0; mt < 2; mt++)
        #pragma unroll
        for (int r = 0; r < 4; r++)
            #pragma unroll
            for (int d = 1; d < 16; d <<= 1) li[mt][r] += __shfl_xor(li[mt][r], d);

    // ---- 4 -> 2 -> 1 tree reduce in LDS (pbuf dead now) ----
    __syncthreads();
    float* red  = (float*)smem;                 // [2][32][128]
    float* redl = (float*)(smem + 32768);       // [2][32]
    if (wave & 1) {                             // waves 1,3 -> slot wave>>1
        const int slot = wave >> 1;
        #pragma unroll
        for (int mt = 0; mt < 2; mt++)
            #pragma unroll
            for (int ht = 0; ht < 8; ht++)
                #pragma unroll
                for (int r = 0; r < 4; r++)
                    red[slot*4096 + (mt*16 + quad*4 + r)*128 + ht*16 + ln] = o[mt][ht][r];
        if (ln == 0)
            #pragma unroll
            for (int mt = 0; mt < 2; mt++)
                #pragma unroll
                for (int r = 0; r < 4; r++)
                    redl[slot*32 + mt*16 + quad*4 + r] = li[mt][r];
    }
    __syncthreads();
    if (!(wave & 1)) {                          // waves 0,2 absorb
        const int slot = wave >> 1;
        #pragma unroll
        for (int mt = 0; mt < 2; mt++) {
            #pragma unroll
            for (int ht = 0; ht < 8; ht++)
                #pragma unroll
                for (int r = 0; r < 4; r++)
                    o[mt][ht][r] += red[slot*4096 + (mt*16 + quad*4 + r)*128 + ht*16 + ln];
            #pragma unroll
            for (int r = 0; r < 4; r++)
                li[mt][r] += redl[slot*32 + mt*16 + quad*4 + r];
        }
    }
    __syncthreads();
    if (wave == 2) {                            // wave 2 -> slot 0
        #pragma unroll
        for (int mt = 0; mt < 2; mt++) {
            #pragma unroll
            for (int ht = 0; ht < 8; ht++)
                #pragma unroll
                for (int r = 0; r < 4; r++)
                    red[(mt*16 + quad*4 + r)*128 + ht*16 + ln] = o[mt][ht][r];
            if (ln == 0)
                #pragma unroll
                for (int r = 0; r < 4; r++)
                    redl[mt*16 + quad*4 + r] = li[mt][r];
        }
    }
    __syncthreads();
    if (wave == 0) {                            // final combine + store
        #pragma unroll
        for (int mt = 0; mt < 2; mt++) {
            #pragma unroll
            for (int r = 0; r < 4; r++)
                li[mt][r] += redl[mt*16 + quad*4 + r];
            #pragma unroll
            for (int ht = 0; ht < 8; ht++)
                #pragma unroll
                for (int r = 0; r < 4; r++) {
                    float v = o[mt][ht][r] + red[(mt*16 + quad*4 + r)*128 + ht*16 + ln];
                    out[((long)b*TT + qb + mt*16 + quad*4 + r)*HD + ht*16 + ln] = v / li[mt][r];
                }
        }
    }
}

extern "C" void kernel_launch(void* const* d_in, const int* in_sizes, int n_in,
                              void* d_out, int out_size, void* d_ws, size_t ws_size,
                              hipStream_t stream) {
    const float* x  = (const float*)d_in[0];
    const float* Wq = (const float*)d_in[1];
    const float* Wk = (const float*)d_in[2];
    const float* Wv = (const float*)d_in[3];
    float* outp = (float*)d_out;

    // ws: Wp 768KB | Q 4MB | Kp 4MB | Vp 4MB  ~= 12.75MB
    bf16* Wp = (bf16*)d_ws;
    bf16* Qm = Wp + (long)NW * CDIM;
    bf16* Kp = Qm + (long)NTOK * HD;
    bf16* Vp = Kp + (long)NTOK * HD;

    prep_w_kernel<<<192, 256, 0, stream>>>(Wq, Wk, Wv, Wp);
    qkv_proj_kernel<<<512, 512, 0, stream>>>(x, Wp, Qm, Kp, Vp);
    attn_kernel<<<NB * 64, 256, 0, stream>>>(Qm, Kp, Vp, outp);
}

// Round 15
// 135.705 us; speedup vs baseline: 1.0549x; 1.0549x over previous
//
#include <hip/hip_runtime.h>
#include <hip/hip_bf16.h>

// Head: x(8,2048,1024) fp32 @ {Wq,Wk,Wv}(1024,128) fp32
//   -> causal softmax((QK^T)/32) @ V -> out FP32.
// Ledger: best 136.8us (R13) = simple 2-phase qkv (41us, 64KB LDS) + QBLK32
// attn with K-dbuf @(256,2). R22 (half-LDS, (512,8)) REGRESSED: grid is 512
// blocks = exactly 2/CU, so the higher cap bought nothing — it only added a
// serial staging phase + a 64-VGPR squeeze. Rule: occupancy caps only matter
// if the grid supplies the blocks.
// R23: revert to R13 + ONE register-safe change: qkv software-prefetches the
// 3 B-frags one k-slice ahead (+~24 VGPR on a 52-56 VGPR kernel, cap 128 at
// (512,4) -> margin ~+50). Attacks the B-load(L2 ~200cyc)->MFMA chain that
// keeps qkv latency-bound (all pipes <=15%). attn/prep frozen (R13 winners).

typedef __attribute__((ext_vector_type(8))) short bf16x8;   // 8 bf16 = 4 VGPRs
typedef __attribute__((ext_vector_type(4))) float f32x4;    // MFMA C/D frag

#define NB   8
#define TT   2048
#define CDIM 1024
#define HD   128
#define NTOK (NB * TT)   // 16384
#define NW   384

using bf16 = __hip_bfloat16;

__device__ __forceinline__ short f2bs(float f) {          // RNE bf16
    unsigned u = __builtin_bit_cast(unsigned, f);
    return (short)((u + 0x7FFF + ((u >> 16) & 1)) >> 16);
}

// ---------- prep: pack W into MFMA B-fragment order ----------
__global__ __launch_bounds__(256) void prep_w_kernel(
        const float* __restrict__ Wq, const float* __restrict__ Wk,
        const float* __restrict__ Wv, bf16* __restrict__ Wp) {
    const int f  = blockIdx.x * 256 + threadIdx.x;        // 0..49151
    const int l  = f & 63;
    const int nt = (f >> 6) % 24;
    const int sl = f / 1536;
    const int ln = l & 15, quad = l >> 4;
    const int n  = nt * 16 + ln;                          // 0..383
    const int w  = n >> 7, h = n & 127;
    const float* W = (w == 0) ? Wq : (w == 1) ? Wk : Wv;
    const int k0 = sl * 32 + quad * 8;
    bf16x8 frag;
    #pragma unroll
    for (int j = 0; j < 8; j++)
        frag[j] = f2bs(W[(long)(k0 + j) * HD + h]);
    *(bf16x8*)((short*)Wp + (long)f * 8) = frag;          // coalesced 16B/thread
}

// ---------- QKV projection: grid 512, block 512 = 8 waves ----------
// 32 rows/block = one attn key-tile; wave w: cols [48w,48w+48).
// Phase 1: x -> bf16 A-frags in LDS (frag-linear, 64KB). Phase 2: 32-slice
// MFMA loop with B-frags software-prefetched one slice ahead (R23).
__global__ __launch_bounds__(512, 4) void qkv_proj_kernel(
        const float* __restrict__ x, const bf16* __restrict__ Wp,
        bf16* __restrict__ Q, bf16* __restrict__ Kp, bf16* __restrict__ Vp) {
    __shared__ __align__(16) short aLDS[2 * 32 * 64 * 8];   // 64KB A-frags
    const int tid  = threadIdx.x;
    const int wave = tid >> 6, lane = tid & 63;
    const int quad = lane >> 4, ln = lane & 15;
    const long mbase = (long)blockIdx.x * 32;

    // ----- phase 1: x -> bf16 frags in LDS (8 frags/thread) -----
    #pragma unroll
    for (int j = 0; j < 8; j++) {
        const int fid = j * 512 + tid;                    // wave-contiguous
        const int fl  = fid & 63;
        const int fsl = (fid >> 6) & 31;
        const int fmt = fid >> 11;
        const float4* src = (const float4*)(
            x + (mbase + fmt * 16 + (fl & 15)) * CDIM + fsl * 32 + (fl >> 4) * 8);
        float4 u = src[0], v = src[1];
        bf16x8 fr;
        fr[0] = f2bs(u.x); fr[1] = f2bs(u.y); fr[2] = f2bs(u.z); fr[3] = f2bs(u.w);
        fr[4] = f2bs(v.x); fr[5] = f2bs(v.y); fr[6] = f2bs(v.z); fr[7] = f2bs(v.w);
        *(bf16x8*)(aLDS + (long)fid * 8) = fr;            // linear: no conflicts
    }
    __syncthreads();

    // ----- phase 2: MFMA main loop over 32 k-slices, B prefetched -----
    const f32x4 zero = {0.f, 0.f, 0.f, 0.f};
    f32x4 acc[2][3];
    #pragma unroll
    for (int mt = 0; mt < 2; mt++)
        #pragma unroll
        for (int nt = 0; nt < 3; nt++) acc[mt][nt] = zero;

    const short* a0 = aLDS + lane * 8;                        // + mt*16384 + sl*512
    const short* bp = (const short*)Wp + (long)wave * 1536 + lane * 8; // + sl*12288 + nt*512

    bf16x8 b0 = *(const bf16x8*)(bp);
    bf16x8 b1 = *(const bf16x8*)(bp + 512);
    bf16x8 b2 = *(const bf16x8*)(bp + 1024);

    #pragma unroll 4
    for (int sl = 0; sl < 32; sl++) {
        bf16x8 cb0 = b0, cb1 = b1, cb2 = b2;
        if (sl + 1 < 32) {                                // prefetch next slice
            b0 = *(const bf16x8*)(bp + (long)(sl + 1) * 12288);
            b1 = *(const bf16x8*)(bp + (long)(sl + 1) * 12288 + 512);
            b2 = *(const bf16x8*)(bp + (long)(sl + 1) * 12288 + 1024);
        }
        bf16x8 af0 = *(const bf16x8*)(a0 + sl * 512);
        bf16x8 af1 = *(const bf16x8*)(a0 + 16384 + sl * 512);
        acc[0][0] = __builtin_amdgcn_mfma_f32_16x16x32_bf16(af0, cb0, acc[0][0], 0, 0, 0);
        acc[0][1] = __builtin_amdgcn_mfma_f32_16x16x32_bf16(af0, cb1, acc[0][1], 0, 0, 0);
        acc[0][2] = __builtin_amdgcn_mfma_f32_16x16x32_bf16(af0, cb2, acc[0][2], 0, 0, 0);
        acc[1][0] = __builtin_amdgcn_mfma_f32_16x16x32_bf16(af1, cb0, acc[1][0], 0, 0, 0);
        acc[1][1] = __builtin_amdgcn_mfma_f32_16x16x32_bf16(af1, cb1, acc[1][1], 0, 0, 0);
        acc[1][2] = __builtin_amdgcn_mfma_f32_16x16x32_bf16(af1, cb2, acc[1][2], 0, 0, 0);
    }

    // ----- epilogue: Q -> global; K,V -> LDS transpose -> packed tiles -----
    __syncthreads();                                      // aLDS dead for all waves
    short* kT = aLDS;                                     // [32][136] shorts
    short* vT = aLDS + 8192;                              // [128][40] shorts

    #pragma unroll
    for (int mt = 0; mt < 2; mt++) {
        #pragma unroll
        for (int nt = 0; nt < 3; nt++) {
            const int n = wave * 48 + nt * 16 + ln;
            #pragma unroll
            for (int r = 0; r < 4; r++) {
                const int row = mt * 16 + quad * 4 + r;   // local token 0..31
                const short hv = f2bs(acc[mt][nt][r]);
                if (n < 128) {
                    long g = mbase + row;
                    int b = (int)(g >> 11), t = (int)(g & (TT - 1));
                    Q[((long)b * TT + t) * HD + n] = __builtin_bit_cast(bf16, hv);
                } else if (n < 256) {
                    kT[row * 136 + (n - 128)] = hv;       // K[tok][h]
                } else {
                    vT[(n - 256) * 40 + row] = hv;        // V^T[h][tok]
                }
            }
        }
    }
    __syncthreads();

    // packed frag writes: wave w emits K frag w (kc=w>>1, nt=w&1) and V frag w
    {
        const long tile = blockIdx.x;                     // = b*64 + jt
        const int  kc = wave >> 1, ntk = wave & 1;
        bf16x8 kv = *(const bf16x8*)&kT[(ntk*16 + ln)*136 + kc*32 + quad*8];
        *(bf16x8*)((short*)Kp + (tile*8 + wave)*512 + lane*8) = kv;
        bf16x8 vv = *(const bf16x8*)&vT[(wave*16 + ln)*40 + quad*8];
        *(bf16x8*)((short*)Vp + (tile*8 + wave)*512 + lane*8) = vv;
    }
}

// ---------- causal flash attention (QBLK=32, K double-buffered) ----------
// Frozen R13 winner. Static-max softmax; grid 512, block 256 = 4 waves;
// waves split the key range, partials tree-reduced in LDS (4 -> 2 -> 1).
// K/V frag loads = contiguous 1KB wave-loads; next tile's K prefetched
// during softmax+PV (live ~212 under the (256,2) cap of 256).
#define ATTN_TILE32(CUR, NXT)                                                    \
  {                                                                              \
    const int j0 = kt * 32;                                                      \
    const short* vbase = Vpb + (long)kt * 4096 + lane * 8;                       \
    bf16x8 vf[8];                                                                \
    _Pragma("unroll")                                                            \
    for (int ht = 0; ht < 8; ht++)                                               \
        vf[ht] = *(const bf16x8*)(vbase + ht*512);                               \
    if (kt + 1 < t1) {                                                           \
        const short* nkb = Kpb + (long)(kt + 1) * 4096 + lane * 8;               \
        _Pragma("unroll")                                                        \
        for (int kc = 0; kc < 4; kc++)                                           \
            _Pragma("unroll")                                                    \
            for (int ntk = 0; ntk < 2; ntk++)                                    \
                NXT[kc][ntk] = *(const bf16x8*)(nkb + (kc*2 + ntk)*512);         \
    }                                                                            \
    f32x4 s[2][2];                                                               \
    s[0][0] = zero; s[0][1] = zero; s[1][0] = zero; s[1][1] = zero;              \
    _Pragma("unroll")                                                            \
    for (int kc = 0; kc < 4; kc++)                                               \
        _Pragma("unroll")                                                        \
        for (int mt = 0; mt < 2; mt++) {                                         \
            s[mt][0] = __builtin_amdgcn_mfma_f32_16x16x32_bf16(qf[mt][kc], CUR[kc][0], s[mt][0], 0, 0, 0); \
            s[mt][1] = __builtin_amdgcn_mfma_f32_16x16x32_bf16(qf[mt][kc], CUR[kc][1], s[mt][1], 0, 0, 0); \
        }                                                                        \
    short* pb = pwave + (kt & 1) * 1280;                                         \
    _Pragma("unroll")                                                            \
    for (int mt = 0; mt < 2; mt++)                                               \
        _Pragma("unroll")                                                        \
        for (int r = 0; r < 4; r++) {                                            \
            const int q = qb + mt*16 + quad*4 + r;                               \
            _Pragma("unroll")                                                    \
            for (int ntk = 0; ntk < 2; ntk++) {                                  \
                float p = __expf(s[mt][ntk][r] * 0.03125f);                      \
                if (j0 + ntk*16 + ln > q) p = 0.f;                               \
                li[mt][r] += p;                                                  \
                pb[(mt*16 + quad*4 + r)*40 + ntk*16 + ln] = f2bs(p);             \
            }                                                                    \
        }                                                                        \
    bf16x8 pf[2];                                                                \
    _Pragma("unroll")                                                            \
    for (int mt = 0; mt < 2; mt++)                                               \
        pf[mt] = *(const bf16x8*)&pb[(mt*16 + ln)*40 + quad*8];                  \
    _Pragma("unroll")                                                            \
    for (int mt = 0; mt < 2; mt++)                                               \
        _Pragma("unroll")                                                        \
        for (int ht = 0; ht < 8; ht++)                                           \
            o[mt][ht] = __builtin_amdgcn_mfma_f32_16x16x32_bf16(pf[mt], vf[ht], o[mt][ht], 0, 0, 0); \
    kt++;                                                                        \
  }

__global__ __launch_bounds__(256, 2) void attn_kernel(
        const bf16* __restrict__ Q, const bf16* __restrict__ Kp,
        const bf16* __restrict__ Vp, float* __restrict__ out) {
    // union: pbuf (4 waves x 2 x [32][40] shorts = 20480B, live in loop)
    //        red [2][32][128] f32 = 32768B + redl [2][32] f32 = 256B, after
    __shared__ __align__(16) char smem[33024];

    const int tid  = threadIdx.x;
    const int wave = tid >> 6, lane = tid & 63;
    const int quad = lane >> 4, ln = lane & 15;
    // block -> (b, qi): balanced pairing {63-r, r}
    const int b   = blockIdx.x & 7;
    const int idx = blockIdx.x >> 3;           // 0..63
    const int qi  = (idx >> 5) ? (idx & 31) : 63 - (idx & 31);
    const int qb  = qi * 32;
    const int ntiles = qi + 1;                 // key tiles of 32
    const int t0 = (ntiles * wave) >> 2;
    const int t1 = (ntiles * (wave + 1)) >> 2;

    const bf16*  Qb  = Q + (long)b * TT * HD;
    const short* Kpb = (const short*)Kp + (long)b * 64 * 4096;  // 4096 sh/tile
    const short* Vpb = (const short*)Vp + (long)b * 64 * 4096;

    short* pwave = (short*)smem + wave * 2560;             // 2 x [32][40]

    bf16x8 qf[2][4];
    #pragma unroll
    for (int mt = 0; mt < 2; mt++)
        #pragma unroll
        for (int kc = 0; kc < 4; kc++)
            qf[mt][kc] = *(const bf16x8*)(Qb + (long)(qb + mt*16 + ln)*HD + kc*32 + quad*8);

    const f32x4 zero = {0.f, 0.f, 0.f, 0.f};
    f32x4 o[2][8];
    #pragma unroll
    for (int mt = 0; mt < 2; mt++)
        #pragma unroll
        for (int ht = 0; ht < 8; ht++) o[mt][ht] = zero;
    float li[2][4] = {{0.f,0.f,0.f,0.f},{0.f,0.f,0.f,0.f}};

    bf16x8 kfA[4][2], kfB[4][2];
    if (t0 < t1) {
        const short* kb0 = Kpb + (long)t0 * 4096 + lane * 8;
        #pragma unroll
        for (int kc = 0; kc < 4; kc++)
            #pragma unroll
            for (int ntk = 0; ntk < 2; ntk++)
                kfA[kc][ntk] = *(const bf16x8*)(kb0 + (kc*2 + ntk)*512);
    }
    int kt = t0;
    while (kt < t1) {
        ATTN_TILE32(kfA, kfB)
        if (kt >= t1) break;
        ATTN_TILE32(kfB, kfA)
    }

    // reduce li across the 16 lanes sharing each row
    #pragma unroll
    for (int mt = 0; mt < 2; mt++)
        #pragma unroll
        for (int r = 0; r < 4; r++)
            #pragma unroll
            for (int d = 1; d < 16; d <<= 1) li[mt][r] += __shfl_xor(li[mt][r], d);

    // ---- 4 -> 2 -> 1 tree reduce in LDS (pbuf dead now) ----
    __syncthreads();
    float* red  = (float*)smem;                 // [2][32][128]
    float* redl = (float*)(smem + 32768);       // [2][32]
    if (wave & 1) {                             // waves 1,3 -> slot wave>>1
        const int slot = wave >> 1;
        #pragma unroll
        for (int mt = 0; mt < 2; mt++)
            #pragma unroll
            for (int ht = 0; ht < 8; ht++)
                #pragma unroll
                for (int r = 0; r < 4; r++)
                    red[slot*4096 + (mt*16 + quad*4 + r)*128 + ht*16 + ln] = o[mt][ht][r];
        if (ln == 0)
            #pragma unroll
            for (int mt = 0; mt < 2; mt++)
                #pragma unroll
                for (int r = 0; r < 4; r++)
                    redl[slot*32 + mt*16 + quad*4 + r] = li[mt][r];
    }
    __syncthreads();
    if (!(wave & 1)) {                          // waves 0,2 absorb
        const int slot = wave >> 1;
        #pragma unroll
        for (int mt = 0; mt < 2; mt++) {
            #pragma unroll
            for (int ht = 0; ht < 8; ht++)
                #pragma unroll
                for (int r = 0; r < 4; r++)
                    o[mt][ht][r] += red[slot*4096 + (mt*16 + quad*4 + r)*128 + ht*16 + ln];
            #pragma unroll
            for (int r = 0; r < 4; r++)
                li[mt][r] += redl[slot*32 + mt*16 + quad*4 + r];
        }
    }
    __syncthreads();
    if (wave == 2) {                            // wave 2 -> slot 0
        #pragma unroll
        for (int mt = 0; mt < 2; mt++) {
            #pragma unroll
            for (int ht = 0; ht < 8; ht++)
                #pragma unroll
                for (int r = 0; r < 4; r++)
                    red[(mt*16 + quad*4 + r)*128 + ht*16 + ln] = o[mt][ht][r];
            if (ln == 0)
                #pragma unroll
                for (int r = 0; r < 4; r++)
                    redl[mt*16 + quad*4 + r] = li[mt][r];
        }
    }
    __syncthreads();
    if (wave == 0) {                            // final combine + store
        #pragma unroll
        for (int mt = 0; mt < 2; mt++) {
            #pragma unroll
            for (int r = 0; r < 4; r++)
                li[mt][r] += redl[mt*16 + quad*4 + r];
            #pragma unroll
            for (int ht = 0; ht < 8; ht++)
                #pragma unroll
                for (int r = 0; r < 4; r++) {
                    float v = o[mt][ht][r] + red[(mt*16 + quad*4 + r)*128 + ht*16 + ln];
                    out[((long)b*TT + qb + mt*16 + quad*4 + r)*HD + ht*16 + ln] = v / li[mt][r];
                }
        }
    }
}

extern "C" void kernel_launch(void* const* d_in, const int* in_sizes, int n_in,
                              void* d_out, int out_size, void* d_ws, size_t ws_size,
                              hipStream_t stream) {
    const float* x  = (const float*)d_in[0];
    const float* Wq = (const float*)d_in[1];
    const float* Wk = (const float*)d_in[2];
    const float* Wv = (const float*)d_in[3];
    float* outp = (float*)d_out;

    // ws: Wp 768KB | Q 4MB | Kp 4MB | Vp 4MB  ~= 12.75MB
    bf16* Wp = (bf16*)d_ws;
    bf16* Qm = Wp + (long)NW * CDIM;
    bf16* Kp = Qm + (long)NTOK * HD;
    bf16* Vp = Kp + (long)NTOK * HD;

    prep_w_kernel<<<192, 256, 0, stream>>>(Wq, Wk, Wv, Wp);
    qkv_proj_kernel<<<512, 512, 0, stream>>>(x, Wp, Qm, Kp, Vp);
    attn_kernel<<<NB * 64, 256, 0, stream>>>(Qm, Kp, Vp, outp);
}

// Round 17
// 133.740 us; speedup vs baseline: 1.0704x; 1.0147x over previous
//
#include <hip/hip_runtime.h>
#include <hip/hip_bf16.h>

// Head: x(8,2048,1024) fp32 @ {Wq,Wk,Wv}(1024,128) fp32
//   -> causal softmax((QK^T)/32) @ V -> out FP32.
// Ledger: best 135.7us (R15) = 2-phase qkv (43us) + QBLK32 attn K-dbuf
// @(256,2). qkv's ~65K unexplained cyc/CU matches the phase-1 TA gather
// (frag-ordered lanes = 64 discontiguous 16B segments per wave-instr).
// R24 staged row-major+XOR but had a coverage bug: 4 chunks staged only
// 32KB of the 64KB tile (rows 16..31 uninitialized -> NaN).
// R25: same layout, 8 chunks (p=c*512+tid, c<8 -> rows 0..31). Each
// wave-instr covers 2KB contiguous src / 1KB LDS. Write = linear lanes
// (conflict-free), read = 2-way XOR alias (free, m136). Phase 2 /
// epilogue / attn / prep frozen (R15 winners).

typedef __attribute__((ext_vector_type(8))) short bf16x8;   // 8 bf16 = 4 VGPRs
typedef __attribute__((ext_vector_type(4))) float f32x4;    // MFMA C/D frag

#define NB   8
#define TT   2048
#define CDIM 1024
#define HD   128
#define NTOK (NB * TT)   // 16384
#define NW   384

using bf16 = __hip_bfloat16;

__device__ __forceinline__ short f2bs(float f) {          // RNE bf16
    unsigned u = __builtin_bit_cast(unsigned, f);
    return (short)((u + 0x7FFF + ((u >> 16) & 1)) >> 16);
}

// ---------- prep: pack W into MFMA B-fragment order ----------
__global__ __launch_bounds__(256) void prep_w_kernel(
        const float* __restrict__ Wq, const float* __restrict__ Wk,
        const float* __restrict__ Wv, bf16* __restrict__ Wp) {
    const int f  = blockIdx.x * 256 + threadIdx.x;        // 0..49151
    const int l  = f & 63;
    const int nt = (f >> 6) % 24;
    const int sl = f / 1536;
    const int ln = l & 15, quad = l >> 4;
    const int n  = nt * 16 + ln;                          // 0..383
    const int w  = n >> 7, h = n & 127;
    const float* W = (w == 0) ? Wq : (w == 1) ? Wk : Wv;
    const int k0 = sl * 32 + quad * 8;
    bf16x8 frag;
    #pragma unroll
    for (int j = 0; j < 8; j++)
        frag[j] = f2bs(W[(long)(k0 + j) * HD + h]);
    *(bf16x8*)((short*)Wp + (long)f * 8) = frag;          // coalesced 16B/thread
}

// ---------- QKV projection: grid 512, block 512 = 8 waves ----------
// 32 rows/block = one attn key-tile; wave w: cols [48w,48w+48).
// Phase 1 (R25): coalesced staging — chunk c covers pair p = c*512+tid
// (8 chunks -> all 4096 pairs), row = p>>7, 2KB contiguous per wave-instr;
// LDS row-major [32][1024] bf16, byte ^= (row&7)<<4. Phase 2: 32-slice MFMA.
__global__ __launch_bounds__(512, 4) void qkv_proj_kernel(
        const float* __restrict__ x, const bf16* __restrict__ Wp,
        bf16* __restrict__ Q, bf16* __restrict__ Kp, bf16* __restrict__ Vp) {
    __shared__ __align__(16) short aLDS[32 * 1024];         // 64KB
    const int tid  = threadIdx.x;
    const int wave = tid >> 6, lane = tid & 63;
    const int quad = lane >> 4, ln = lane & 15;
    const long mbase = (long)blockIdx.x * 32;

    // ----- phase 1: x -> bf16 rows in LDS (8 chunks of 32B src / 16B dst) --
    char* aB = (char*)aLDS;
    #pragma unroll
    for (int c = 0; c < 8; c++) {
        const int p   = c * 512 + tid;         // pair index 0..4095
        const int row = p >> 7;                // 128 pairs per row -> 0..31
        const int pc  = p & 127;
        const float4* src = (const float4*)(x + (mbase + row) * CDIM + pc * 8);
        float4 u = src[0], v = src[1];
        bf16x8 fr;
        fr[0] = f2bs(u.x); fr[1] = f2bs(u.y); fr[2] = f2bs(u.z); fr[3] = f2bs(u.w);
        fr[4] = f2bs(v.x); fr[5] = f2bs(v.y); fr[6] = f2bs(v.z); fr[7] = f2bs(v.w);
        *(bf16x8*)(aB + ((row * 2048 + pc * 16) ^ ((row & 7) << 4))) = fr;
    }
    __syncthreads();

    // ----- phase 2: MFMA main loop over 32 k-slices (B prefetch, R15) -----
    const f32x4 zero = {0.f, 0.f, 0.f, 0.f};
    f32x4 acc[2][3];
    #pragma unroll
    for (int mt = 0; mt < 2; mt++)
        #pragma unroll
        for (int nt = 0; nt < 3; nt++) acc[mt][nt] = zero;

    const char* a0 = aB + ln * 2048;           // mt=1 at +32768
    const int   xorv = (ln & 7) << 4;
    const short* bp = (const short*)Wp + (long)wave * 1536 + lane * 8;

    bf16x8 b0 = *(const bf16x8*)(bp);
    bf16x8 b1 = *(const bf16x8*)(bp + 512);
    bf16x8 b2 = *(const bf16x8*)(bp + 1024);

    #pragma unroll 4
    for (int sl = 0; sl < 32; sl++) {
        bf16x8 cb0 = b0, cb1 = b1, cb2 = b2;
        if (sl + 1 < 32) {                                // prefetch next slice
            b0 = *(const bf16x8*)(bp + (long)(sl + 1) * 12288);
            b1 = *(const bf16x8*)(bp + (long)(sl + 1) * 12288 + 512);
            b2 = *(const bf16x8*)(bp + (long)(sl + 1) * 12288 + 1024);
        }
        const int cb = (sl * 64 + quad * 16) ^ xorv;
        bf16x8 af0 = *(const bf16x8*)(a0 + cb);
        bf16x8 af1 = *(const bf16x8*)(a0 + 32768 + cb);
        acc[0][0] = __builtin_amdgcn_mfma_f32_16x16x32_bf16(af0, cb0, acc[0][0], 0, 0, 0);
        acc[0][1] = __builtin_amdgcn_mfma_f32_16x16x32_bf16(af0, cb1, acc[0][1], 0, 0, 0);
        acc[0][2] = __builtin_amdgcn_mfma_f32_16x16x32_bf16(af0, cb2, acc[0][2], 0, 0, 0);
        acc[1][0] = __builtin_amdgcn_mfma_f32_16x16x32_bf16(af1, cb0, acc[1][0], 0, 0, 0);
        acc[1][1] = __builtin_amdgcn_mfma_f32_16x16x32_bf16(af1, cb1, acc[1][1], 0, 0, 0);
        acc[1][2] = __builtin_amdgcn_mfma_f32_16x16x32_bf16(af1, cb2, acc[1][2], 0, 0, 0);
    }

    // ----- epilogue: Q -> global; K,V -> LDS transpose -> packed tiles -----
    __syncthreads();                                      // aLDS dead for all waves
    short* kT = aLDS;                                     // [32][136] shorts
    short* vT = aLDS + 8192;                              // [128][40] shorts

    #pragma unroll
    for (int mt = 0; mt < 2; mt++) {
        #pragma unroll
        for (int nt = 0; nt < 3; nt++) {
            const int n = wave * 48 + nt * 16 + ln;
            #pragma unroll
            for (int r = 0; r < 4; r++) {
                const int row = mt * 16 + quad * 4 + r;   // local token 0..31
                const short hv = f2bs(acc[mt][nt][r]);
                if (n < 128) {
                    long g = mbase + row;
                    int b = (int)(g >> 11), t = (int)(g & (TT - 1));
                    Q[((long)b * TT + t) * HD + n] = __builtin_bit_cast(bf16, hv);
                } else if (n < 256) {
                    kT[row * 136 + (n - 128)] = hv;       // K[tok][h]
                } else {
                    vT[(n - 256) * 40 + row] = hv;        // V^T[h][tok]
                }
            }
        }
    }
    __syncthreads();

    // packed frag writes: wave w emits K frag w (kc=w>>1, nt=w&1) and V frag w
    {
        const long tile = blockIdx.x;                     // = b*64 + jt
        const int  kc = wave >> 1, ntk = wave & 1;
        bf16x8 kv = *(const bf16x8*)&kT[(ntk*16 + ln)*136 + kc*32 + quad*8];
        *(bf16x8*)((short*)Kp + (tile*8 + wave)*512 + lane*8) = kv;
        bf16x8 vv = *(const bf16x8*)&vT[(wave*16 + ln)*40 + quad*8];
        *(bf16x8*)((short*)Vp + (tile*8 + wave)*512 + lane*8) = vv;
    }
}

// ---------- causal flash attention (QBLK=32, K double-buffered) ----------
// Frozen R13 winner. Static-max softmax; grid 512, block 256 = 4 waves;
// waves split the key range, partials tree-reduced in LDS (4 -> 2 -> 1).
// K/V frag loads = contiguous 1KB wave-loads; next tile's K prefetched
// during softmax+PV (live ~212 under the (256,2) cap of 256).
#define ATTN_TILE32(CUR, NXT)                                                    \
  {                                                                              \
    const int j0 = kt * 32;                                                      \
    const short* vbase = Vpb + (long)kt * 4096 + lane * 8;                       \
    bf16x8 vf[8];                                                                \
    _Pragma("unroll")                                                            \
    for (int ht = 0; ht < 8; ht++)                                               \
        vf[ht] = *(const bf16x8*)(vbase + ht*512);                               \
    if (kt + 1 < t1) {                                                           \
        const short* nkb = Kpb + (long)(kt + 1) * 4096 + lane * 8;               \
        _Pragma("unroll")                                                        \
        for (int kc = 0; kc < 4; kc++)                                           \
            _Pragma("unroll")                                                    \
            for (int ntk = 0; ntk < 2; ntk++)                                    \
                NXT[kc][ntk] = *(const bf16x8*)(nkb + (kc*2 + ntk)*512);         \
    }                                                                            \
    f32x4 s[2][2];                                                               \
    s[0][0] = zero; s[0][1] = zero; s[1][0] = zero; s[1][1] = zero;              \
    _Pragma("unroll")                                                            \
    for (int kc = 0; kc < 4; kc++)                                               \
        _Pragma("unroll")                                                        \
        for (int mt = 0; mt < 2; mt++) {                                         \
            s[mt][0] = __builtin_amdgcn_mfma_f32_16x16x32_bf16(qf[mt][kc], CUR[kc][0], s[mt][0], 0, 0, 0); \
            s[mt][1] = __builtin_amdgcn_mfma_f32_16x16x32_bf16(qf[mt][kc], CUR[kc][1], s[mt][1], 0, 0, 0); \
        }                                                                        \
    short* pb = pwave + (kt & 1) * 1280;                                         \
    _Pragma("unroll")                                                            \
    for (int mt = 0; mt < 2; mt++)                                               \
        _Pragma("unroll")                                                        \
        for (int r = 0; r < 4; r++) {                                            \
            const int q = qb + mt*16 + quad*4 + r;                               \
            _Pragma("unroll")                                                    \
            for (int ntk = 0; ntk < 2; ntk++) {                                  \
                float p = __expf(s[mt][ntk][r] * 0.03125f);                      \
                if (j0 + ntk*16 + ln > q) p = 0.f;                               \
                li[mt][r] += p;                                                  \
                pb[(mt*16 + quad*4 + r)*40 + ntk*16 + ln] = f2bs(p);             \
            }                                                                    \
        }                                                                        \
    bf16x8 pf[2];                                                                \
    _Pragma("unroll")                                                            \
    for (int mt = 0; mt < 2; mt++)                                               \
        pf[mt] = *(const bf16x8*)&pb[(mt*16 + ln)*40 + quad*8];                  \
    _Pragma("unroll")                                                            \
    for (int mt = 0; mt < 2; mt++)                                               \
        _Pragma("unroll")                                                        \
        for (int ht = 0; ht < 8; ht++)                                           \
            o[mt][ht] = __builtin_amdgcn_mfma_f32_16x16x32_bf16(pf[mt], vf[ht], o[mt][ht], 0, 0, 0); \
    kt++;                                                                        \
  }

__global__ __launch_bounds__(256, 2) void attn_kernel(
        const bf16* __restrict__ Q, const bf16* __restrict__ Kp,
        const bf16* __restrict__ Vp, float* __restrict__ out) {
    // union: pbuf (4 waves x 2 x [32][40] shorts = 20480B, live in loop)
    //        red [2][32][128] f32 = 32768B + redl [2][32] f32 = 256B, after
    __shared__ __align__(16) char smem[33024];

    const int tid  = threadIdx.x;
    const int wave = tid >> 6, lane = tid & 63;
    const int quad = lane >> 4, ln = lane & 15;
    // block -> (b, qi): balanced pairing {63-r, r}
    const int b   = blockIdx.x & 7;
    const int idx = blockIdx.x >> 3;           // 0..63
    const int qi  = (idx >> 5) ? (idx & 31) : 63 - (idx & 31);
    const int qb  = qi * 32;
    const int ntiles = qi + 1;                 // key tiles of 32
    const int t0 = (ntiles * wave) >> 2;
    const int t1 = (ntiles * (wave + 1)) >> 2;

    const bf16*  Qb  = Q + (long)b * TT * HD;
    const short* Kpb = (const short*)Kp + (long)b * 64 * 4096;  // 4096 sh/tile
    const short* Vpb = (const short*)Vp + (long)b * 64 * 4096;

    short* pwave = (short*)smem + wave * 2560;             // 2 x [32][40]

    bf16x8 qf[2][4];
    #pragma unroll
    for (int mt = 0; mt < 2; mt++)
        #pragma unroll
        for (int kc = 0; kc < 4; kc++)
            qf[mt][kc] = *(const bf16x8*)(Qb + (long)(qb + mt*16 + ln)*HD + kc*32 + quad*8);

    const f32x4 zero = {0.f, 0.f, 0.f, 0.f};
    f32x4 o[2][8];
    #pragma unroll
    for (int mt = 0; mt < 2; mt++)
        #pragma unroll
        for (int ht = 0; ht < 8; ht++) o[mt][ht] = zero;
    float li[2][4] = {{0.f,0.f,0.f,0.f},{0.f,0.f,0.f,0.f}};

    bf16x8 kfA[4][2], kfB[4][2];
    if (t0 < t1) {
        const short* kb0 = Kpb + (long)t0 * 4096 + lane * 8;
        #pragma unroll
        for (int kc = 0; kc < 4; kc++)
            #pragma unroll
            for (int ntk = 0; ntk < 2; ntk++)
                kfA[kc][ntk] = *(const bf16x8*)(kb0 + (kc*2 + ntk)*512);
    }
    int kt = t0;
    while (kt < t1) {
        ATTN_TILE32(kfA, kfB)
        if (kt >= t1) break;
        ATTN_TILE32(kfB, kfA)
    }

    // reduce li across the 16 lanes sharing each row
    #pragma unroll
    for (int mt = 0; mt < 2; mt++)
        #pragma unroll
        for (int r = 0; r < 4; r++)
            #pragma unroll
            for (int d = 1; d < 16; d <<= 1) li[mt][r] += __shfl_xor(li[mt][r], d);

    // ---- 4 -> 2 -> 1 tree reduce in LDS (pbuf dead now) ----
    __syncthreads();
    float* red  = (float*)smem;                 // [2][32][128]
    float* redl = (float*)(smem + 32768);       // [2][32]
    if (wave & 1) {                             // waves 1,3 -> slot wave>>1
        const int slot = wave >> 1;
        #pragma unroll
        for (int mt = 0; mt < 2; mt++)
            #pragma unroll
            for (int ht = 0; ht < 8; ht++)
                #pragma unroll
                for (int r = 0; r < 4; r++)
                    red[slot*4096 + (mt*16 + quad*4 + r)*128 + ht*16 + ln] = o[mt][ht][r];
        if (ln == 0)
            #pragma unroll
            for (int mt = 0; mt < 2; mt++)
                #pragma unroll
                for (int r = 0; r < 4; r++)
                    redl[slot*32 + mt*16 + quad*4 + r] = li[mt][r];
    }
    __syncthreads();
    if (!(wave & 1)) {                          // waves 0,2 absorb
        const int slot = wave >> 1;
        #pragma unroll
        for (int mt = 0; mt < 2; mt++) {
            #pragma unroll
            for (int ht = 0; ht < 8; ht++)
                #pragma unroll
                for (int r = 0; r < 4; r++)
                    o[mt][ht][r] += red[slot*4096 + (mt*16 + quad*4 + r)*128 + ht*16 + ln];
            #pragma unroll
            for (int r = 0; r < 4; r++)
                li[mt][r] += redl[slot*32 + mt*16 + quad*4 + r];
        }
    }
    __syncthreads();
    if (wave == 2) {                            // wave 2 -> slot 0
        #pragma unroll
        for (int mt = 0; mt < 2; mt++) {
            #pragma unroll
            for (int ht = 0; ht < 8; ht++)
                #pragma unroll
                for (int r = 0; r < 4; r++)
                    red[(mt*16 + quad*4 + r)*128 + ht*16 + ln] = o[mt][ht][r];
            if (ln == 0)
                #pragma unroll
                for (int r = 0; r < 4; r++)
                    redl[mt*16 + quad*4 + r] = li[mt][r];
        }
    }
    __syncthreads();
    if (wave == 0) {                            // final combine + store
        #pragma unroll
        for (int mt = 0; mt < 2; mt++) {
            #pragma unroll
            for (int r = 0; r < 4; r++)
                li[mt][r] += redl[mt*16 + quad*4 + r];
            #pragma unroll
            for (int ht = 0; ht < 8; ht++)
                #pragma unroll
                for (int r = 0; r < 4; r++) {
                    float v = o[mt][ht][r] + red[(mt*16 + quad*4 + r)*128 + ht*16 + ln];
                    out[((long)b*TT + qb + mt*16 + quad*4 + r)*HD + ht*16 + ln] = v / li[mt][r];
                }
        }
    }
}

extern "C" void kernel_launch(void* const* d_in, const int* in_sizes, int n_in,
                              void* d_out, int out_size, void* d_ws, size_t ws_size,
                              hipStream_t stream) {
    const float* x  = (const float*)d_in[0];
    const float* Wq = (const float*)d_in[1];
    const float* Wk = (const float*)d_in[2];
    const float* Wv = (const float*)d_in[3];
    float* outp = (float*)d_out;

    // ws: Wp 768KB | Q 4MB | Kp 4MB | Vp 4MB  ~= 12.75MB
    bf16* Wp = (bf16*)d_ws;
    bf16* Qm = Wp + (long)NW * CDIM;
    bf16* Kp = Qm + (long)NTOK * HD;
    bf16* Vp = Kp + (long)NTOK * HD;

    prep_w_kernel<<<192, 256, 0, stream>>>(Wq, Wk, Wv, Wp);
    qkv_proj_kernel<<<512, 512, 0, stream>>>(x, Wp, Qm, Kp, Vp);
    attn_kernel<<<NB * 64, 256, 0, stream>>>(Qm, Kp, Vp, outp);
}